// Round 12
// baseline (116.476 us; speedup 1.0000x reference)
//
#include <hip/hip_runtime.h>

typedef unsigned short u16;
typedef unsigned int u32;
typedef unsigned long long u64;
typedef __attribute__((ext_vector_type(8))) short short8;
typedef __attribute__((ext_vector_type(4))) float f32x4;
typedef __attribute__((ext_vector_type(4))) u32 u32x4;

#define BATCH 8
#define NSEQ 1024
#define DMODEL 512
#define HDIM 64
// QK_SCALE * log2(e): softmax computed in exp2 domain
#define SCALE_LOG2E 0.06375871114929199f
#define FIXED_MAX 16.0f

// workspace byte offsets
#define O_QBF 0ULL
#define O_KBF 8388608ULL
#define O_WB  16777216ULL
#define O_MB  18874368ULL
#define O_QP  19922944ULL
#define O_KP  28311552ULL
#define O_VP  36700160ULL

__device__ __forceinline__ u16 f2bf(float f) {
  u32 u = __float_as_uint(f);
  u = (u + 0x7fffu + ((u >> 16) & 1u)) >> 16;
  return (u16)u;
}
__device__ __forceinline__ float bf2f(u16 s) {
  return __uint_as_float(((u32)s) << 16);
}
__device__ __forceinline__ void gload16(const void* g, void* l) {
  __builtin_amdgcn_global_load_lds((const __attribute__((address_space(1))) void*)g,
                                   (__attribute__((address_space(3))) void*)l, 16, 0, 0);
}
// pack two f32 -> u32 of 2 bf16 (lo = a, hi = b), RNE — same rounding as f2bf
__device__ __forceinline__ u32 cvtpk(float a, float b) {
  u32 r;
  asm("v_cvt_pk_bf16_f32 %0, %1, %2" : "=v"(r) : "v"(a), "v"(b));
  return r;
}

// ---------------------------------------------------------------------------
// prep: transpose-convert weights to [N][K]; pack M into u64 bitmask words.
// (Q/K fp32->bf16 conversion is now fused into gemm1's A-staging.)
// ---------------------------------------------------------------------------
__global__ __launch_bounds__(256) void prep_kernel(
    const float* __restrict__ Wq, const float* __restrict__ Wk,
    const float* __restrict__ Wv, const float* __restrict__ Wo,
    const int* __restrict__ M,
    u16* __restrict__ Wb, u64* __restrict__ Mb)
{
  __shared__ float lds[64 * 68];
  const int bi = blockIdx.x, t = threadIdx.x;
  if (bi < 256) {
    const int w = bi >> 6;
    const int tt = bi & 63;
    const int tr = tt >> 3, tc = tt & 7;          // 64x64 tile at (tr*64 k, tc*64 n)
    const float* W = (w == 0) ? Wq : (w == 1) ? Wk : (w == 2) ? Wv : Wo;
#pragma unroll
    for (int j = 0; j < 4; ++j) {
      int vi = j * 256 + t;
      int row = vi >> 4, c4 = vi & 15;
      float4 v = *(const float4*)(W + (size_t)(tr * 64 + row) * 512 + tc * 64 + c4 * 4);
      lds[row * 68 + c4 * 4 + 0] = v.x;
      lds[row * 68 + c4 * 4 + 1] = v.y;
      lds[row * 68 + c4 * 4 + 2] = v.z;
      lds[row * 68 + c4 * 4 + 3] = v.w;
    }
    __syncthreads();
    // 64 n-rows x 8 k8-chunks = 512 short8 stores -> exactly 2 iterations
#pragma unroll
    for (int j = 0; j < 2; ++j) {
      int oi = j * 256 + t;
      int nl = oi >> 3, k8 = oi & 7;
      short8 o;
#pragma unroll
      for (int i = 0; i < 8; ++i) o[i] = (short)f2bf(lds[(k8 * 8 + i) * 68 + nl]);
      *(short8*)(Wb + (size_t)w * 262144 + (size_t)(tc * 64 + nl) * 512 + tr * 64 + k8 * 8) = o;
    }
  } else {
    // pack M to bits: word (b,q,kc) bit k = M[b][q][kc*64+k] != 0  (r2-proven)
    const int pb = bi - 256;                      // 1024 blocks
    const int wv = t >> 6, lane = t & 63;
    for (int i = 0; i < 32; ++i) {
      int widx = pb * 128 + wv * 32 + i;          // < 131072
      int kc = widx & 15;
      int qq = (widx >> 4) & 1023;
      int bb = widx >> 14;
      int mv = M[((size_t)bb * 1024 + qq) * 1024 + kc * 64 + lane];
      u64 bal = __ballot(mv != 0);
      if (lane == 0) Mb[widx] = bal;
    }
  }
}

// ---------------------------------------------------------------------------
// gemm_bt: C[M=8192,N=512] = A[M,512] * Wb^T (Wb stored [N][K]) + bias
// MODE 0: A is RAW FP32 (Q or K input) — fp32->bf16 conversion fused into
//   the A-staging (float4 loads -> cvt_pk -> ds_write_b128; dest byte addr
//   idx*16 is identical to the gload_lds layout). Kills the Qbf/Kbf
//   round-trip (67 MB of traffic + half of prep).
// MODE 1: A is bf16 (Xn), staged via global_load_lds as before.
// 1-D grid, XCD-locality: block p -> XCD p%8; A panels L2-resident.
// ---------------------------------------------------------------------------
template<int MODE>
__global__ __launch_bounds__(256) void gemm_bt(
    const float* __restrict__ Fq, const float* __restrict__ Fk,
    const u16* __restrict__ Abf,
    const u16* __restrict__ Wb,
    const float* __restrict__ b0, const float* __restrict__ b1, const float* __restrict__ b2,
    u16* __restrict__ outp, const u16* __restrict__ resid)
{
  __shared__ __align__(16) char Alds[8192];
  __shared__ __align__(16) char Blds[8192];
  const int tid = threadIdx.x;
  const int wv = tid >> 6, lane = tid & 63;
  const int g16 = lane >> 4, l16 = lane & 15;
  const int wr = wv >> 1, wc = wv & 1;

  const int p = blockIdx.x;
  const int xcd = p & 7, rest = p >> 3;
  const int bx = xcd + ((rest & 7) << 3);        // 0..63
  const int q2 = rest >> 3;                      // MODE0: 0..11, MODE1: 0..3
  const int by = (MODE == 0) ? (q2 & 3) : q2;
  const int bz = (MODE == 0) ? (q2 >> 2) : 0;

  const float* Af; const u16* A; const u16* W; const float* bias; u16* out;
  if (MODE == 0) {
    Af = (bz == 0) ? Fq : Fk;
    A = nullptr;
    W = Wb + (size_t)bz * 262144;
    bias = (bz == 0) ? b0 : ((bz == 1) ? b1 : b2);
    out = outp + (size_t)bz * 4194304;
  } else {
    Af = nullptr; A = Abf; W = Wb; bias = b0; out = outp;
  }

  const int m0 = bx * 128, n0 = by * 128;
  f32x4 acc[4][4] = {};

  for (int kt = 0; kt < 16; ++kt) {
    const int k0 = kt * 32;
#pragma unroll
    for (int r = 0; r < 2; ++r) {
      int idx = r * 256 + tid;
      int row = idx >> 2, sl = idx & 3;
      if (MODE == 0) {
        const float* ap = Af + (size_t)(m0 + row) * 512 + k0 + sl * 8;
        float4 a0 = *(const float4*)(ap);
        float4 a1 = *(const float4*)(ap + 4);
        u32x4 wpk;
        wpk[0] = cvtpk(a0.x, a0.y);
        wpk[1] = cvtpk(a0.z, a0.w);
        wpk[2] = cvtpk(a1.x, a1.y);
        wpk[3] = cvtpk(a1.z, a1.w);
        *(u32x4*)(Alds + (size_t)idx * 16) = wpk;   // idx*16 == r*4096 + tid*16
      } else {
        gload16(A + (size_t)(m0 + row) * 512 + k0 + sl * 8, Alds + r * 4096 + wv * 1024);
      }
      gload16(W + (size_t)(n0 + row) * 512 + k0 + sl * 8, Blds + r * 4096 + wv * 1024);
    }
    __syncthreads();
    short8 af[4], bfr[4];
#pragma unroll
    for (int mt = 0; mt < 4; ++mt)
      af[mt] = *(const short8*)(Alds + (wr * 64 + mt * 16 + l16) * 64 + g16 * 16);
#pragma unroll
    for (int nt = 0; nt < 4; ++nt)
      bfr[nt] = *(const short8*)(Blds + (wc * 64 + nt * 16 + l16) * 64 + g16 * 16);
#pragma unroll
    for (int mt = 0; mt < 4; ++mt)
#pragma unroll
      for (int nt = 0; nt < 4; ++nt)
        acc[mt][nt] = __builtin_amdgcn_mfma_f32_16x16x32_bf16(af[mt], bfr[nt], acc[mt][nt], 0, 0, 0);
    __syncthreads();
  }

#pragma unroll
  for (int nt = 0; nt < 4; ++nt) {
    int col = n0 + wc * 64 + nt * 16 + l16;
    float bcol = bias[col];
#pragma unroll
    for (int mt = 0; mt < 4; ++mt) {
#pragma unroll
      for (int r = 0; r < 4; ++r) {
        int row = m0 + wr * 64 + mt * 16 + g16 * 4 + r;
        float v = acc[mt][nt][r] + bcol;
        if (MODE == 1) {
          v = fmaxf(v, 0.f) + bf2f(resid[(size_t)row * 512 + col]);
        }
        out[(size_t)row * 512 + col] = f2bf(v);
      }
    }
  }
}

// ---------------------------------------------------------------------------
// flash attention (r11, best=43us): swapped-operand, static-max softmax,
// lane-local PV (kappa labeling), K via global_load_lds dbuf, V^T reg-staged
// dbuf, packed-u64 mask unpacked in-register to the bias C-in fragment.
// Per tile: s_waitcnt vmcnt(8) lgkmcnt(0) + raw s_barrier (never vmcnt(0)).
// ---------------------------------------------------------------------------
__global__ __launch_bounds__(256, 4) void attn_kernel(
    const u16* __restrict__ Qp, const u16* __restrict__ Kp, const u16* __restrict__ Vp,
    const u64* __restrict__ Mb, u16* __restrict__ O1)
{
  __shared__ __align__(16) char K_lds[2][8192];    // [64 k][64 dk] bf16, chunk-swizzled
  __shared__ __align__(16) char VT_lds[2][8192];   // [64 dv][64 kappa] bf16, chunk-swizzled

  const int tid = threadIdx.x;
  const int wv = tid >> 6, lane = tid & 63;
  const int g16 = lane >> 4, l16 = lane & 15;
  const int l7 = l16 & 7;

  // bijective XCD swizzle: all 16 q-tiles of a (b,h) share one XCD's L2
  const int wg = blockIdx.x;                       // 1024 blocks
  const int swz = (wg & 7) * 128 + (wg >> 3);
  const int qt = swz & 15;
  const int h = (swz >> 4) & 7;
  const int b = swz >> 7;
  const int qg = qt * 64;
  const int hb = h * HDIM;
  const size_t batch_row = (size_t)b * NSEQ;

  const int q = qg + wv * 16 + l16;                // this lane's q column
  const int dv2 = (tid & 31) * 2;                  // V staging lanes
  const int kg = tid >> 5;                         // 0..7 = kc*4+gg
  const int v_kc = kg >> 2, v_gg = kg & 3;

  // hoist Q as B-operand frags, pre-scaled into the exp2 domain
  short8 b_q[2];
#pragma unroll
  for (int c = 0; c < 2; ++c) {
    short8 raw = *(const short8*)(Qp + (batch_row + q) * DMODEL + hb + c * 32 + g16 * 8);
    short8 sc;
#pragma unroll
    for (int j = 0; j < 8; ++j) sc[j] = (short)f2bf(bf2f((u16)raw[j]) * SCALE_LOG2E);
    b_q[c] = sc;
  }

  const u64* Mq = Mb + (batch_row + q) * 16;

  auto stageK = [&](int kt2, char* dst) {
#pragma unroll
    for (int r = 0; r < 2; ++r) {
      int idx = r * 256 + tid;
      int row = idx >> 3, sl = idx & 7;
      int chunk = sl ^ (row & 7);
      gload16(Kp + (batch_row + kt2 * 64 + row) * DMODEL + hb + chunk * 8,
              dst + r * 4096 + wv * 1024);
    }
  };
  // load V rows in kappa order (lane-local PV labeling, verified r9)
  auto loadV = [&](int kt2, u32 (&vr)[8]) {
#pragma unroll
    for (int j = 0; j < 8; ++j) {
      int row = v_kc * 32 + (j >> 2) * 16 + v_gg * 4 + (j & 3);
      vr[j] = *(const u32*)(Vp + (batch_row + kt2 * 64 + row) * DMODEL + hb + dv2);
    }
  };
  auto writeVT = [&](const u32 (&vr)[8], char* dstv) {
    u32x4 lo, hi;
#pragma unroll
    for (int i = 0; i < 4; ++i) {
      lo[i] = __builtin_amdgcn_perm(vr[2 * i + 1], vr[2 * i], 0x05040100u);
      hi[i] = __builtin_amdgcn_perm(vr[2 * i + 1], vr[2 * i], 0x07060302u);
    }
    *(u32x4*)(dstv + dv2 * 128 + ((kg ^ (dv2 & 7)) << 4)) = lo;
    *(u32x4*)(dstv + (dv2 + 1) * 128 + ((kg ^ ((dv2 + 1) & 7)) << 4)) = hi;
  };

  float lL = 0.f;
  f32x4 accO[4] = {};

  u32 vreg[8];
  u64 mksA, mksB;

  // prologue: stage tile 0; entering tile 0 the queue is mks0[<=1], V1[8]
  stageK(0, &K_lds[0][0]);
  loadV(0, vreg);
  mksA = Mq[0];
  writeVT(vreg, &VT_lds[0][0]);   // compiler-counted wait retires K0+V0 here
  loadV(1, vreg);

#define ATTN_TILE(KT, CUR, MKS, MKSN)                                          \
  do {                                                                         \
    asm volatile("s_waitcnt vmcnt(8) lgkmcnt(0)" ::: "memory");                \
    __builtin_amdgcn_sched_barrier(0);                                         \
    __builtin_amdgcn_s_barrier();                                              \
    __builtin_amdgcn_sched_barrier(0);                                         \
    char* Kc = &K_lds[CUR][0];                                                 \
    char* Vc = &VT_lds[CUR][0];                                                \
    if ((KT) < 15) {                                                           \
      writeVT(vreg, &VT_lds[(CUR) ^ 1][0]);                                    \
      stageK((KT) + 1, &K_lds[(CUR) ^ 1][0]);                                  \
      loadV((KT) + 2 < 16 ? (KT) + 2 : 15, vreg);                              \
      MKSN = Mq[(KT) + 1];                                                     \
    }                                                                          \
    f32x4 s_[4];                                                               \
    __builtin_amdgcn_s_setprio(1);                                             \
    _Pragma("unroll")                                                          \
    for (int kf = 0; kf < 4; ++kf) {                                           \
      int row = kf * 16 + l16;                                                 \
      short8 ak0 = *(const short8*)(Kc + row * 128 + ((g16 ^ l7) << 4));       \
      short8 ak1 = *(const short8*)(Kc + row * 128 + (((4 + g16) ^ l7) << 4)); \
      u32 nib = ((u32)((MKS) >> (kf * 16 + g16 * 4))) & 15u;                   \
      f32x4 acc;                                                               \
      acc[0] = (nib & 1u) ? 0.f : -32768.f;                                    \
      acc[1] = (nib & 2u) ? 0.f : -32768.f;                                    \
      acc[2] = (nib & 4u) ? 0.f : -32768.f;                                    \
      acc[3] = (nib & 8u) ? 0.f : -32768.f;                                    \
      acc = __builtin_amdgcn_mfma_f32_16x16x32_bf16(ak0, b_q[0], acc, 0, 0, 0);\
      acc = __builtin_amdgcn_mfma_f32_16x16x32_bf16(ak1, b_q[1], acc, 0, 0, 0);\
      s_[kf] = acc;                                                            \
    }                                                                          \
    __builtin_amdgcn_s_setprio(0);                                             \
    float sum = 0.f;                                                           \
    u32 c0a[4], c1a[4];                                                        \
    _Pragma("unroll")                                                          \
    for (int kf = 0; kf < 4; ++kf) {                                           \
      float e0 = __builtin_amdgcn_exp2f(s_[kf][0] - FIXED_MAX);                \
      float e1 = __builtin_amdgcn_exp2f(s_[kf][1] - FIXED_MAX);                \
      float e2 = __builtin_amdgcn_exp2f(s_[kf][2] - FIXED_MAX);                \
      float e3 = __builtin_amdgcn_exp2f(s_[kf][3] - FIXED_MAX);                \
      sum += (e0 + e1) + (e2 + e3);                                            \
      c0a[kf] = cvtpk(e0, e1);                                                 \
      c1a[kf] = cvtpk(e2, e3);                                                 \
    }                                                                          \
    lL += sum;                                                                 \
    u32x4 t0 = {c0a[0], c1a[0], c0a[1], c1a[1]};                               \
    u32x4 t1 = {c0a[2], c1a[2], c0a[3], c1a[3]};                               \
    short8 b_p0 = *(short8*)&t0;                                               \
    short8 b_p1 = *(short8*)&t1;                                               \
    __builtin_amdgcn_s_setprio(1);                                             \
    _Pragma("unroll")                                                          \
    for (int f = 0; f < 4; ++f) {                                              \
      int vrow = f * 16 + l16;                                                 \
      short8 av0 = *(const short8*)(Vc + vrow * 128 + ((g16 ^ l7) << 4));      \
      short8 av1 = *(const short8*)(Vc + vrow * 128 + (((4 + g16) ^ l7) << 4));\
      accO[f] = __builtin_amdgcn_mfma_f32_16x16x32_bf16(av0, b_p0, accO[f], 0, 0, 0); \
      accO[f] = __builtin_amdgcn_mfma_f32_16x16x32_bf16(av1, b_p1, accO[f], 0, 0, 0); \
    }                                                                          \
    __builtin_amdgcn_s_setprio(0);                                             \
  } while (0)

  for (int t = 0; t < 8; ++t) {
    ATTN_TILE(2 * t, 0, mksA, mksB);
    ATTN_TILE(2 * t + 1, 1, mksB, mksA);
  }
#undef ATTN_TILE

  // epilogue: reduce l across g16 groups once; O = Qh + accO^T / l
  float l = lL;
  l += __shfl_xor(l, 16, 64);
  l += __shfl_xor(l, 32, 64);
  float inv = 1.0f / fmaxf(l, 1e-20f);
#pragma unroll
  for (int f = 0; f < 4; ++f) {
    size_t o = (batch_row + q) * DMODEL + hb + f * 16 + g16 * 4;
    u64 qh = *(const u64*)(Qp + o);
    u64 ov = 0;
#pragma unroll
    for (int r = 0; r < 4; ++r) {
      float val = accO[f][r] * inv + bf2f((u16)(qh >> (r * 16)));
      ov |= ((u64)f2bf(val)) << (r * 16);
    }
    *(u64*)(O1 + o) = ov;
  }
}

// ---------------------------------------------------------------------------
// layernorm: one wave per 512-ch row. OUTF=0 -> bf16 out, OUTF=1 -> fp32 out
// ---------------------------------------------------------------------------
template<int OUTF>
__global__ __launch_bounds__(256) void ln_kernel(
    const u16* __restrict__ X, const float* __restrict__ g, const float* __restrict__ bb,
    void* __restrict__ outv)
{
  const int tid = threadIdx.x;
  const int wv = tid >> 6, lane = tid & 63;
  const size_t row = (size_t)blockIdx.x * 4 + wv;
  short8 x8 = *(const short8*)(X + row * 512 + lane * 8);
  float xf[8];
  float s = 0.f, s2 = 0.f;
#pragma unroll
  for (int i = 0; i < 8; ++i) {
    xf[i] = bf2f((u16)x8[i]);
    s += xf[i];
    s2 += xf[i] * xf[i];
  }
#pragma unroll
  for (int d = 1; d < 64; d <<= 1) {
    s += __shfl_xor(s, d, 64);
    s2 += __shfl_xor(s2, d, 64);
  }
  float mu = s * (1.f / 512.f);
  float var = s2 * (1.f / 512.f) - mu * mu;
  float rs = rsqrtf(var + 1e-5f);
  float4 ga = *(const float4*)(g + lane * 8);
  float4 gb = *(const float4*)(g + lane * 8 + 4);
  float4 ba = *(const float4*)(bb + lane * 8);
  float4 bc = *(const float4*)(bb + lane * 8 + 4);
  float gv[8] = {ga.x, ga.y, ga.z, ga.w, gb.x, gb.y, gb.z, gb.w};
  float bv[8] = {ba.x, ba.y, ba.z, ba.w, bc.x, bc.y, bc.z, bc.w};
  float y[8];
#pragma unroll
  for (int i = 0; i < 8; ++i) y[i] = (xf[i] - mu) * rs * gv[i] + bv[i];
  if (OUTF) {
    float* o = (float*)outv + row * 512 + lane * 8;
    float4 o1 = {y[0], y[1], y[2], y[3]};
    float4 o2 = {y[4], y[5], y[6], y[7]};
    *(float4*)o = o1;
    *(float4*)(o + 4) = o2;
  } else {
    short8 o;
#pragma unroll
    for (int i = 0; i < 8; ++i) o[i] = (short)f2bf(y[i]);
    *(short8*)((u16*)outv + row * 512 + lane * 8) = o;
  }
}

// ---------------------------------------------------------------------------
extern "C" void kernel_launch(void* const* d_in, const int* in_sizes, int n_in,
                              void* d_out, int out_size, void* d_ws, size_t ws_size,
                              hipStream_t stream) {
  (void)in_sizes; (void)n_in; (void)out_size; (void)ws_size;
  const float* Q  = (const float*)d_in[0];
  const float* K  = (const float*)d_in[1];
  const float* Wq = (const float*)d_in[2];
  const float* bq = (const float*)d_in[3];
  const float* Wk = (const float*)d_in[4];
  const float* bk = (const float*)d_in[5];
  const float* Wv = (const float*)d_in[6];
  const float* bv = (const float*)d_in[7];
  const float* Wo = (const float*)d_in[8];
  const float* bo = (const float*)d_in[9];
  const float* g0 = (const float*)d_in[10];
  const float* b0 = (const float*)d_in[11];
  const float* g1 = (const float*)d_in[12];
  const float* b1 = (const float*)d_in[13];
  const int*   M  = (const int*)d_in[14];
  float* out = (float*)d_out;
  char* ws = (char*)d_ws;

  u16* Wb  = (u16*)(ws + O_WB);
  u64* Mb  = (u64*)(ws + O_MB);
  u16* Qp  = (u16*)(ws + O_QP);
  u16* Kp  = (u16*)(ws + O_KP);
  u16* Vp  = (u16*)(ws + O_VP);
  u16* O1  = (u16*)(ws + O_QBF);  // free region (Qbf/Kbf no longer exist)
  u16* Xn  = Qp;                  // Qp dead after attn
  u16* Z   = (u16*)(ws + O_KBF);

  prep_kernel<<<1280, 256, 0, stream>>>(Wq, Wk, Wv, Wo, M, Wb, Mb);
  gemm_bt<0><<<768, 256, 0, stream>>>(Q, K, nullptr, Wb, bq, bk, bv, Qp, nullptr);
  attn_kernel<<<1024, 256, 0, stream>>>(Qp, Kp, Vp, Mb, O1);
  ln_kernel<0><<<2048, 256, 0, stream>>>(O1, g0, b0, (void*)Xn);
  gemm_bt<1><<<256, 256, 0, stream>>>(nullptr, nullptr, Xn, Wb + 3 * 262144, bo,
                                      nullptr, nullptr, Z, Xn);
  ln_kernel<1><<<2048, 256, 0, stream>>>(Z, g1, b1, (void*)out);
}

// Round 13
// 115.485 us; speedup vs baseline: 1.0086x; 1.0086x over previous
//
#include <hip/hip_runtime.h>

typedef unsigned short u16;
typedef unsigned int u32;
typedef unsigned long long u64;
typedef __attribute__((ext_vector_type(8))) short short8;
typedef __attribute__((ext_vector_type(4))) float f32x4;
typedef __attribute__((ext_vector_type(4))) u32 u32x4;

#define BATCH 8
#define NSEQ 1024
#define DMODEL 512
#define HDIM 64
// QK_SCALE * log2(e): softmax computed in exp2 domain
#define SCALE_LOG2E 0.06375871114929199f
#define FIXED_MAX 16.0f

// workspace byte offsets
#define O_QBF 0ULL
#define O_KBF 8388608ULL
#define O_WB  16777216ULL
#define O_MB  18874368ULL
#define O_QP  19922944ULL
#define O_KP  28311552ULL
#define O_VP  36700160ULL

__device__ __forceinline__ u16 f2bf(float f) {
  u32 u = __float_as_uint(f);
  u = (u + 0x7fffu + ((u >> 16) & 1u)) >> 16;
  return (u16)u;
}
__device__ __forceinline__ float bf2f(u16 s) {
  return __uint_as_float(((u32)s) << 16);
}
__device__ __forceinline__ void gload16(const void* g, void* l) {
  __builtin_amdgcn_global_load_lds((const __attribute__((address_space(1))) void*)g,
                                   (__attribute__((address_space(3))) void*)l, 16, 0, 0);
}
// pack two f32 -> u32 of 2 bf16 (lo = a, hi = b), RNE — same rounding as f2bf
__device__ __forceinline__ u32 cvtpk(float a, float b) {
  u32 r;
  asm("v_cvt_pk_bf16_f32 %0, %1, %2" : "=v"(r) : "v"(a), "v"(b));
  return r;
}

// ---------------------------------------------------------------------------
// prep: transpose-convert weights to [N][K] only (M-pack folded into gemm1,
// Q/K fp32->bf16 fused into gemm1's A-staging).
// ---------------------------------------------------------------------------
__global__ __launch_bounds__(256) void prep_kernel(
    const float* __restrict__ Wq, const float* __restrict__ Wk,
    const float* __restrict__ Wv, const float* __restrict__ Wo,
    u16* __restrict__ Wb)
{
  __shared__ float lds[64 * 68];
  const int bi = blockIdx.x, t = threadIdx.x;
  const int w = bi >> 6;
  const int tt = bi & 63;
  const int tr = tt >> 3, tc = tt & 7;          // 64x64 tile at (tr*64 k, tc*64 n)
  const float* W = (w == 0) ? Wq : (w == 1) ? Wk : (w == 2) ? Wv : Wo;
#pragma unroll
  for (int j = 0; j < 4; ++j) {
    int vi = j * 256 + t;
    int row = vi >> 4, c4 = vi & 15;
    float4 v = *(const float4*)(W + (size_t)(tr * 64 + row) * 512 + tc * 64 + c4 * 4);
    lds[row * 68 + c4 * 4 + 0] = v.x;
    lds[row * 68 + c4 * 4 + 1] = v.y;
    lds[row * 68 + c4 * 4 + 2] = v.z;
    lds[row * 68 + c4 * 4 + 3] = v.w;
  }
  __syncthreads();
  // 64 n-rows x 8 k8-chunks = 512 short8 stores -> exactly 2 iterations
#pragma unroll
  for (int j = 0; j < 2; ++j) {
    int oi = j * 256 + t;
    int nl = oi >> 3, k8 = oi & 7;
    short8 o;
#pragma unroll
    for (int i = 0; i < 8; ++i) o[i] = (short)f2bf(lds[(k8 * 8 + i) * 68 + nl]);
    *(short8*)(Wb + (size_t)w * 262144 + (size_t)(tc * 64 + nl) * 512 + tr * 64 + k8 * 8) = o;
  }
}

// ---------------------------------------------------------------------------
// gemm_bt: C[M=8192,N=512] = A[M,512] * Wb^T (Wb stored [N][K]) + bias
// MODE 0 (blocks 0..767): A is RAW FP32; A-tile register-double-buffered one
//   kt ahead (4 float4/thread), cvtpk -> ds_write at stage time. Barriers are
//   COUNTED: compute-entry = s_waitcnt vmcnt(4) lgkmcnt(0) + raw s_barrier.
//   Order-pinned queue at entry: W(kt)[2 gload_lds, older] + A(kt+1)[4 loads,
//   newer] -> vmcnt(4) retires exactly W; A prefetch never drained (never
//   vmcnt(0) in loop; clamped tail load keeps geometry at kt=15).
// MODE 0 blocks 768..1791: M-pack ballot blocks (pure BW, no LDS/barriers) —
//   overlap the mask packing with the latency-bound GEMM.
// MODE 1: bf16 A via global_load_lds, plain __syncthreads (r11-proven).
// 1-D grid, XCD-locality: block p -> XCD p%8; A panels L2-resident.
// ---------------------------------------------------------------------------
template<int MODE>
__global__ __launch_bounds__(256) void gemm_bt(
    const float* __restrict__ Fq, const float* __restrict__ Fk,
    const u16* __restrict__ Abf,
    const u16* __restrict__ Wb,
    const float* __restrict__ b0, const float* __restrict__ b1, const float* __restrict__ b2,
    u16* __restrict__ outp, const u16* __restrict__ resid,
    const int* __restrict__ M, u64* __restrict__ Mb)
{
  __shared__ __align__(16) char Alds[8192];
  __shared__ __align__(16) char Blds[8192];
  const int tid = threadIdx.x;
  const int p = blockIdx.x;

  if (MODE == 0 && p >= 768) {
    // ---- M-pack tail blocks (r2-proven ballot packing) ----
    const int pb = p - 768;                      // 0..1023
    const int wvp = tid >> 6, lane = tid & 63;
    for (int i = 0; i < 32; ++i) {
      int widx = pb * 128 + wvp * 32 + i;        // < 131072
      int kc = widx & 15;
      int qq = (widx >> 4) & 1023;
      int bb = widx >> 14;
      int mv = M[((size_t)bb * 1024 + qq) * 1024 + kc * 64 + lane];
      u64 bal = __ballot(mv != 0);
      if (lane == 0) Mb[widx] = bal;
    }
    return;
  }

  const int wv = tid >> 6, lane = tid & 63;
  const int g16 = lane >> 4, l16 = lane & 15;
  const int wr = wv >> 1, wc = wv & 1;

  const int xcd = p & 7, rest = p >> 3;
  const int bx = xcd + ((rest & 7) << 3);        // 0..63
  const int q2 = rest >> 3;                      // MODE0: 0..11, MODE1: 0..3
  const int by = (MODE == 0) ? (q2 & 3) : q2;
  const int bz = (MODE == 0) ? (q2 >> 2) : 0;

  const float* Af; const u16* A; const u16* W; const float* bias; u16* out;
  if (MODE == 0) {
    Af = (bz == 0) ? Fq : Fk;
    A = nullptr;
    W = Wb + (size_t)bz * 262144;
    bias = (bz == 0) ? b0 : ((bz == 1) ? b1 : b2);
    out = outp + (size_t)bz * 4194304;
  } else {
    Af = nullptr; A = Abf; W = Wb; bias = b0; out = outp;
  }

  const int m0 = bx * 128, n0 = by * 128;
  f32x4 acc[4][4] = {};

  if (MODE == 0) {
    const int row0 = tid >> 2, sl0 = tid & 3;          // idx0 = tid
    const int row1 = (256 + tid) >> 2, sl1 = tid & 3;  // idx1 = 256+tid
    float4 ar[4];
    auto loadA = [&](int kt2) {
      const float* a0 = Af + (size_t)(m0 + row0) * 512 + kt2 * 32 + sl0 * 8;
      const float* a1 = Af + (size_t)(m0 + row1) * 512 + kt2 * 32 + sl1 * 8;
      ar[0] = *(const float4*)(a0);
      ar[1] = *(const float4*)(a0 + 4);
      ar[2] = *(const float4*)(a1);
      ar[3] = *(const float4*)(a1 + 4);
    };
    auto writeA = [&]() {
      u32x4 w0, w1;
      w0[0] = cvtpk(ar[0].x, ar[0].y); w0[1] = cvtpk(ar[0].z, ar[0].w);
      w0[2] = cvtpk(ar[1].x, ar[1].y); w0[3] = cvtpk(ar[1].z, ar[1].w);
      w1[0] = cvtpk(ar[2].x, ar[2].y); w1[1] = cvtpk(ar[2].z, ar[2].w);
      w1[2] = cvtpk(ar[3].x, ar[3].y); w1[3] = cvtpk(ar[3].z, ar[3].w);
      *(u32x4*)(Alds + (size_t)tid * 16) = w0;
      *(u32x4*)(Alds + (size_t)(256 + tid) * 16) = w1;
    };
    auto stageW = [&](int kt2) {
#pragma unroll
      for (int r = 0; r < 2; ++r) {
        int idx = r * 256 + tid;
        int row = idx >> 2, sl = idx & 3;
        gload16(W + (size_t)(n0 + row) * 512 + kt2 * 32 + sl * 8, Blds + r * 4096 + wv * 1024);
      }
    };

    // prologue: A(0) regs -> LDS; W(0) gload; A(1) regs in flight
    loadA(0);
    stageW(0);
    writeA();            // compiler-counted wait retires A(0) loads, W stays
    loadA(1);

    for (int kt = 0; kt < 16; ++kt) {
      // compute-entry: retire W(kt) only; A(kt+1) prefetch stays in flight
      asm volatile("s_waitcnt vmcnt(4) lgkmcnt(0)" ::: "memory");
      __builtin_amdgcn_sched_barrier(0);
      __builtin_amdgcn_s_barrier();
      __builtin_amdgcn_sched_barrier(0);

      short8 af[4], bfr[4];
#pragma unroll
      for (int mt = 0; mt < 4; ++mt)
        af[mt] = *(const short8*)(Alds + (wr * 64 + mt * 16 + l16) * 64 + g16 * 16);
#pragma unroll
      for (int nt = 0; nt < 4; ++nt)
        bfr[nt] = *(const short8*)(Blds + (wc * 64 + nt * 16 + l16) * 64 + g16 * 16);
#pragma unroll
      for (int mt = 0; mt < 4; ++mt)
#pragma unroll
        for (int nt = 0; nt < 4; ++nt)
          acc[mt][nt] = __builtin_amdgcn_mfma_f32_16x16x32_bf16(af[mt], bfr[nt], acc[mt][nt], 0, 0, 0);

      // compute-exit barrier (LDS reuse only; no vmcnt drain)
      __builtin_amdgcn_sched_barrier(0);
      __builtin_amdgcn_s_barrier();
      __builtin_amdgcn_sched_barrier(0);

      if (kt < 15) {
        stageW(kt + 1);                          // W gloads first (older)
        __builtin_amdgcn_sched_barrier(0);
        writeA();                                // waits A(kt+1) regs, W stays
        __builtin_amdgcn_sched_barrier(0);
        loadA(kt + 2 < 16 ? kt + 2 : 15);        // newest; clamp keeps queue
      }
    }
  } else {
    for (int kt = 0; kt < 16; ++kt) {
      const int k0 = kt * 32;
#pragma unroll
      for (int r = 0; r < 2; ++r) {
        int idx = r * 256 + tid;
        int row = idx >> 2, sl = idx & 3;
        gload16(A + (size_t)(m0 + row) * 512 + k0 + sl * 8, Alds + r * 4096 + wv * 1024);
        gload16(W + (size_t)(n0 + row) * 512 + k0 + sl * 8, Blds + r * 4096 + wv * 1024);
      }
      __syncthreads();
      short8 af[4], bfr[4];
#pragma unroll
      for (int mt = 0; mt < 4; ++mt)
        af[mt] = *(const short8*)(Alds + (wr * 64 + mt * 16 + l16) * 64 + g16 * 16);
#pragma unroll
      for (int nt = 0; nt < 4; ++nt)
        bfr[nt] = *(const short8*)(Blds + (wc * 64 + nt * 16 + l16) * 64 + g16 * 16);
#pragma unroll
      for (int mt = 0; mt < 4; ++mt)
#pragma unroll
        for (int nt = 0; nt < 4; ++nt)
          acc[mt][nt] = __builtin_amdgcn_mfma_f32_16x16x32_bf16(af[mt], bfr[nt], acc[mt][nt], 0, 0, 0);
      __syncthreads();
    }
  }

#pragma unroll
  for (int nt = 0; nt < 4; ++nt) {
    int col = n0 + wc * 64 + nt * 16 + l16;
    float bcol = bias[col];
#pragma unroll
    for (int mt = 0; mt < 4; ++mt) {
#pragma unroll
      for (int r = 0; r < 4; ++r) {
        int row = m0 + wr * 64 + mt * 16 + g16 * 4 + r;
        float v = acc[mt][nt][r] + bcol;
        if (MODE == 1) {
          v = fmaxf(v, 0.f) + bf2f(resid[(size_t)row * 512 + col]);
        }
        out[(size_t)row * 512 + col] = f2bf(v);
      }
    }
  }
}

// ---------------------------------------------------------------------------
// flash attention (r11, best=43us): swapped-operand, static-max softmax,
// lane-local PV (kappa labeling), K via global_load_lds dbuf, V^T reg-staged
// dbuf, packed-u64 mask unpacked in-register to the bias C-in fragment.
// Per tile: s_waitcnt vmcnt(8) lgkmcnt(0) + raw s_barrier (never vmcnt(0)).
// ---------------------------------------------------------------------------
__global__ __launch_bounds__(256, 4) void attn_kernel(
    const u16* __restrict__ Qp, const u16* __restrict__ Kp, const u16* __restrict__ Vp,
    const u64* __restrict__ Mb, u16* __restrict__ O1)
{
  __shared__ __align__(16) char K_lds[2][8192];    // [64 k][64 dk] bf16, chunk-swizzled
  __shared__ __align__(16) char VT_lds[2][8192];   // [64 dv][64 kappa] bf16, chunk-swizzled

  const int tid = threadIdx.x;
  const int wv = tid >> 6, lane = tid & 63;
  const int g16 = lane >> 4, l16 = lane & 15;
  const int l7 = l16 & 7;

  // bijective XCD swizzle: all 16 q-tiles of a (b,h) share one XCD's L2
  const int wg = blockIdx.x;                       // 1024 blocks
  const int swz = (wg & 7) * 128 + (wg >> 3);
  const int qt = swz & 15;
  const int h = (swz >> 4) & 7;
  const int b = swz >> 7;
  const int qg = qt * 64;
  const int hb = h * HDIM;
  const size_t batch_row = (size_t)b * NSEQ;

  const int q = qg + wv * 16 + l16;                // this lane's q column
  const int dv2 = (tid & 31) * 2;                  // V staging lanes
  const int kg = tid >> 5;                         // 0..7 = kc*4+gg
  const int v_kc = kg >> 2, v_gg = kg & 3;

  // hoist Q as B-operand frags, pre-scaled into the exp2 domain
  short8 b_q[2];
#pragma unroll
  for (int c = 0; c < 2; ++c) {
    short8 raw = *(const short8*)(Qp + (batch_row + q) * DMODEL + hb + c * 32 + g16 * 8);
    short8 sc;
#pragma unroll
    for (int j = 0; j < 8; ++j) sc[j] = (short)f2bf(bf2f((u16)raw[j]) * SCALE_LOG2E);
    b_q[c] = sc;
  }

  const u64* Mq = Mb + (batch_row + q) * 16;

  auto stageK = [&](int kt2, char* dst) {
#pragma unroll
    for (int r = 0; r < 2; ++r) {
      int idx = r * 256 + tid;
      int row = idx >> 3, sl = idx & 7;
      int chunk = sl ^ (row & 7);
      gload16(Kp + (batch_row + kt2 * 64 + row) * DMODEL + hb + chunk * 8,
              dst + r * 4096 + wv * 1024);
    }
  };
  // load V rows in kappa order (lane-local PV labeling, verified r9)
  auto loadV = [&](int kt2, u32 (&vr)[8]) {
#pragma unroll
    for (int j = 0; j < 8; ++j) {
      int row = v_kc * 32 + (j >> 2) * 16 + v_gg * 4 + (j & 3);
      vr[j] = *(const u32*)(Vp + (batch_row + kt2 * 64 + row) * DMODEL + hb + dv2);
    }
  };
  auto writeVT = [&](const u32 (&vr)[8], char* dstv) {
    u32x4 lo, hi;
#pragma unroll
    for (int i = 0; i < 4; ++i) {
      lo[i] = __builtin_amdgcn_perm(vr[2 * i + 1], vr[2 * i], 0x05040100u);
      hi[i] = __builtin_amdgcn_perm(vr[2 * i + 1], vr[2 * i], 0x07060302u);
    }
    *(u32x4*)(dstv + dv2 * 128 + ((kg ^ (dv2 & 7)) << 4)) = lo;
    *(u32x4*)(dstv + (dv2 + 1) * 128 + ((kg ^ ((dv2 + 1) & 7)) << 4)) = hi;
  };

  float lL = 0.f;
  f32x4 accO[4] = {};

  u32 vreg[8];
  u64 mksA, mksB;

  // prologue: stage tile 0; entering tile 0 the queue is mks0[<=1], V1[8]
  stageK(0, &K_lds[0][0]);
  loadV(0, vreg);
  mksA = Mq[0];
  writeVT(vreg, &VT_lds[0][0]);   // compiler-counted wait retires K0+V0 here
  loadV(1, vreg);

#define ATTN_TILE(KT, CUR, MKS, MKSN)                                          \
  do {                                                                         \
    asm volatile("s_waitcnt vmcnt(8) lgkmcnt(0)" ::: "memory");                \
    __builtin_amdgcn_sched_barrier(0);                                         \
    __builtin_amdgcn_s_barrier();                                              \
    __builtin_amdgcn_sched_barrier(0);                                         \
    char* Kc = &K_lds[CUR][0];                                                 \
    char* Vc = &VT_lds[CUR][0];                                                \
    if ((KT) < 15) {                                                           \
      writeVT(vreg, &VT_lds[(CUR) ^ 1][0]);                                    \
      stageK((KT) + 1, &K_lds[(CUR) ^ 1][0]);                                  \
      loadV((KT) + 2 < 16 ? (KT) + 2 : 15, vreg);                              \
      MKSN = Mq[(KT) + 1];                                                     \
    }                                                                          \
    f32x4 s_[4];                                                               \
    __builtin_amdgcn_s_setprio(1);                                             \
    _Pragma("unroll")                                                          \
    for (int kf = 0; kf < 4; ++kf) {                                           \
      int row = kf * 16 + l16;                                                 \
      short8 ak0 = *(const short8*)(Kc + row * 128 + ((g16 ^ l7) << 4));       \
      short8 ak1 = *(const short8*)(Kc + row * 128 + (((4 + g16) ^ l7) << 4)); \
      u32 nib = ((u32)((MKS) >> (kf * 16 + g16 * 4))) & 15u;                   \
      f32x4 acc;                                                               \
      acc[0] = (nib & 1u) ? 0.f : -32768.f;                                    \
      acc[1] = (nib & 2u) ? 0.f : -32768.f;                                    \
      acc[2] = (nib & 4u) ? 0.f : -32768.f;                                    \
      acc[3] = (nib & 8u) ? 0.f : -32768.f;                                    \
      acc = __builtin_amdgcn_mfma_f32_16x16x32_bf16(ak0, b_q[0], acc, 0, 0, 0);\
      acc = __builtin_amdgcn_mfma_f32_16x16x32_bf16(ak1, b_q[1], acc, 0, 0, 0);\
      s_[kf] = acc;                                                            \
    }                                                                          \
    __builtin_amdgcn_s_setprio(0);                                             \
    float sum = 0.f;                                                           \
    u32 c0a[4], c1a[4];                                                        \
    _Pragma("unroll")                                                          \
    for (int kf = 0; kf < 4; ++kf) {                                           \
      float e0 = __builtin_amdgcn_exp2f(s_[kf][0] - FIXED_MAX);                \
      float e1 = __builtin_amdgcn_exp2f(s_[kf][1] - FIXED_MAX);                \
      float e2 = __builtin_amdgcn_exp2f(s_[kf][2] - FIXED_MAX);                \
      float e3 = __builtin_amdgcn_exp2f(s_[kf][3] - FIXED_MAX);                \
      sum += (e0 + e1) + (e2 + e3);                                            \
      c0a[kf] = cvtpk(e0, e1);                                                 \
      c1a[kf] = cvtpk(e2, e3);                                                 \
    }                                                                          \
    lL += sum;                                                                 \
    u32x4 t0 = {c0a[0], c1a[0], c0a[1], c1a[1]};                               \
    u32x4 t1 = {c0a[2], c1a[2], c0a[3], c1a[3]};                               \
    short8 b_p0 = *(short8*)&t0;                                               \
    short8 b_p1 = *(short8*)&t1;                                               \
    __builtin_amdgcn_s_setprio(1);                                             \
    _Pragma("unroll")                                                          \
    for (int f = 0; f < 4; ++f) {                                              \
      int vrow = f * 16 + l16;                                                 \
      short8 av0 = *(const short8*)(Vc + vrow * 128 + ((g16 ^ l7) << 4));      \
      short8 av1 = *(const short8*)(Vc + vrow * 128 + (((4 + g16) ^ l7) << 4));\
      accO[f] = __builtin_amdgcn_mfma_f32_16x16x32_bf16(av0, b_p0, accO[f], 0, 0, 0); \
      accO[f] = __builtin_amdgcn_mfma_f32_16x16x32_bf16(av1, b_p1, accO[f], 0, 0, 0); \
    }                                                                          \
    __builtin_amdgcn_s_setprio(0);                                             \
  } while (0)

  for (int t = 0; t < 8; ++t) {
    ATTN_TILE(2 * t, 0, mksA, mksB);
    ATTN_TILE(2 * t + 1, 1, mksB, mksA);
  }
#undef ATTN_TILE

  // epilogue: reduce l across g16 groups once; O = Qh + accO^T / l
  float l = lL;
  l += __shfl_xor(l, 16, 64);
  l += __shfl_xor(l, 32, 64);
  float inv = 1.0f / fmaxf(l, 1e-20f);
#pragma unroll
  for (int f = 0; f < 4; ++f) {
    size_t o = (batch_row + q) * DMODEL + hb + f * 16 + g16 * 4;
    u64 qh = *(const u64*)(Qp + o);
    u64 ov = 0;
#pragma unroll
    for (int r = 0; r < 4; ++r) {
      float val = accO[f][r] * inv + bf2f((u16)(qh >> (r * 16)));
      ov |= ((u64)f2bf(val)) << (r * 16);
    }
    *(u64*)(O1 + o) = ov;
  }
}

// ---------------------------------------------------------------------------
// layernorm: one wave per 512-ch row. OUTF=0 -> bf16 out, OUTF=1 -> fp32 out
// ---------------------------------------------------------------------------
template<int OUTF>
__global__ __launch_bounds__(256) void ln_kernel(
    const u16* __restrict__ X, const float* __restrict__ g, const float* __restrict__ bb,
    void* __restrict__ outv)
{
  const int tid = threadIdx.x;
  const int wv = tid >> 6, lane = tid & 63;
  const size_t row = (size_t)blockIdx.x * 4 + wv;
  short8 x8 = *(const short8*)(X + row * 512 + lane * 8);
  float xf[8];
  float s = 0.f, s2 = 0.f;
#pragma unroll
  for (int i = 0; i < 8; ++i) {
    xf[i] = bf2f((u16)x8[i]);
    s += xf[i];
    s2 += xf[i] * xf[i];
  }
#pragma unroll
  for (int d = 1; d < 64; d <<= 1) {
    s += __shfl_xor(s, d, 64);
    s2 += __shfl_xor(s2, d, 64);
  }
  float mu = s * (1.f / 512.f);
  float var = s2 * (1.f / 512.f) - mu * mu;
  float rs = rsqrtf(var + 1e-5f);
  float4 ga = *(const float4*)(g + lane * 8);
  float4 gb = *(const float4*)(g + lane * 8 + 4);
  float4 ba = *(const float4*)(bb + lane * 8);
  float4 bc = *(const float4*)(bb + lane * 8 + 4);
  float gv[8] = {ga.x, ga.y, ga.z, ga.w, gb.x, gb.y, gb.z, gb.w};
  float bv[8] = {ba.x, ba.y, ba.z, ba.w, bc.x, bc.y, bc.z, bc.w};
  float y[8];
#pragma unroll
  for (int i = 0; i < 8; ++i) y[i] = (xf[i] - mu) * rs * gv[i] + bv[i];
  if (OUTF) {
    float* o = (float*)outv + row * 512 + lane * 8;
    float4 o1 = {y[0], y[1], y[2], y[3]};
    float4 o2 = {y[4], y[5], y[6], y[7]};
    *(float4*)o = o1;
    *(float4*)(o + 4) = o2;
  } else {
    short8 o;
#pragma unroll
    for (int i = 0; i < 8; ++i) o[i] = (short)f2bf(y[i]);
    *(short8*)((u16*)outv + row * 512 + lane * 8) = o;
  }
}

// ---------------------------------------------------------------------------
extern "C" void kernel_launch(void* const* d_in, const int* in_sizes, int n_in,
                              void* d_out, int out_size, void* d_ws, size_t ws_size,
                              hipStream_t stream) {
  (void)in_sizes; (void)n_in; (void)out_size; (void)ws_size;
  const float* Q  = (const float*)d_in[0];
  const float* K  = (const float*)d_in[1];
  const float* Wq = (const float*)d_in[2];
  const float* bq = (const float*)d_in[3];
  const float* Wk = (const float*)d_in[4];
  const float* bk = (const float*)d_in[5];
  const float* Wv = (const float*)d_in[6];
  const float* bv = (const float*)d_in[7];
  const float* Wo = (const float*)d_in[8];
  const float* bo = (const float*)d_in[9];
  const float* g0 = (const float*)d_in[10];
  const float* b0 = (const float*)d_in[11];
  const float* g1 = (const float*)d_in[12];
  const float* b1 = (const float*)d_in[13];
  const int*   M  = (const int*)d_in[14];
  float* out = (float*)d_out;
  char* ws = (char*)d_ws;

  u16* Wb  = (u16*)(ws + O_WB);
  u64* Mb  = (u64*)(ws + O_MB);
  u16* Qp  = (u16*)(ws + O_QP);
  u16* Kp  = (u16*)(ws + O_KP);
  u16* Vp  = (u16*)(ws + O_VP);
  u16* O1  = (u16*)(ws + O_QBF);  // free region
  u16* Xn  = Qp;                  // Qp dead after attn
  u16* Z   = (u16*)(ws + O_KBF);

  prep_kernel<<<256, 256, 0, stream>>>(Wq, Wk, Wv, Wo, Wb);
  gemm_bt<0><<<1792, 256, 0, stream>>>(Q, K, nullptr, Wb, bq, bk, bv, Qp, nullptr, M, Mb);
  attn_kernel<<<1024, 256, 0, stream>>>(Qp, Kp, Vp, Mb, O1);
  ln_kernel<0><<<2048, 256, 0, stream>>>(O1, g0, b0, (void*)Xn);
  gemm_bt<1><<<256, 256, 0, stream>>>(nullptr, nullptr, Xn, Wb + 3 * 262144, bo,
                                      nullptr, nullptr, Z, Xn, nullptr, nullptr);
  ln_kernel<1><<<2048, 256, 0, stream>>>(Z, g1, b1, (void*)out);
}